// Round 1
// baseline (124.154 us; speedup 1.0000x reference)
//
#include <hip/hip_runtime.h>

#define N_NODES 1024
#define B_SZ 64
#define F_IN 10
#define DIM 64
#define TOPK 20
#define BN_TOT (B_SZ * N_NODES)   // 65536

// ---------------- Kernel 1: G = emb @ emb^T (1024x1024, K=64) ----------------
__global__ __launch_bounds__(256) void k_gemm_g(const float* __restrict__ emb,
                                               float* __restrict__ g) {
    __shared__ float As[64][65];
    __shared__ float Bs[64][65];
    const int r0 = blockIdx.y * 64, c0 = blockIdx.x * 64;
    const int t = threadIdx.x;
#pragma unroll
    for (int k = 0; k < 16; ++k) {
        int idx = t + k * 256;          // 0..4095
        int rr = idx >> 6, cc = idx & 63;
        As[rr][cc] = emb[(r0 + rr) * DIM + cc];
        Bs[rr][cc] = emb[(c0 + rr) * DIM + cc];
    }
    __syncthreads();
    const int tx = t & 15, ty = t >> 4;
    float acc[4][4] = {};
#pragma unroll 8
    for (int d = 0; d < 64; ++d) {
        float a[4], b[4];
#pragma unroll
        for (int ii = 0; ii < 4; ++ii) a[ii] = As[ty * 4 + ii][d];
#pragma unroll
        for (int jj = 0; jj < 4; ++jj) b[jj] = Bs[tx * 4 + jj][d];
#pragma unroll
        for (int ii = 0; ii < 4; ++ii)
#pragma unroll
            for (int jj = 0; jj < 4; ++jj) acc[ii][jj] += a[ii] * b[jj];
    }
#pragma unroll
    for (int ii = 0; ii < 4; ++ii)
#pragma unroll
        for (int jj = 0; jj < 4; ++jj)
            g[(r0 + ty * 4 + ii) * N_NODES + (c0 + tx * 4 + jj)] = acc[ii][jj];
}

// ------------- Kernel 2: h = x@W_lin + per-node scalars (+ emb scalars/norms) -------------
__global__ __launch_bounds__(256) void k_hscal(
    const float* __restrict__ data, const float* __restrict__ emb,
    const float* __restrict__ W_lin,
    const float* __restrict__ att_i, const float* __restrict__ att_j,
    const float* __restrict__ att_em_i, const float* __restrict__ att_em_j,
    float* __restrict__ h, float* __restrict__ dscal, float* __restrict__ sscal,
    float* __restrict__ edi, float* __restrict__ esi, float* __restrict__ nrm) {
    const int node = blockIdx.x * 4 + (threadIdx.x >> 6);
    const int d = threadIdx.x & 63;
    float hv = 0.f;
#pragma unroll
    for (int f = 0; f < F_IN; ++f)
        hv += data[node * F_IN + f] * W_lin[f * DIM + d];
    h[node * DIM + d] = hv;
    float s1 = hv * att_i[d];
    float s2 = hv * att_j[d];
#pragma unroll
    for (int m = 32; m >= 1; m >>= 1) {
        s1 += __shfl_xor(s1, m, 64);
        s2 += __shfl_xor(s2, m, 64);
    }
    if (d == 0) { dscal[node] = s1; sscal[node] = s2; }
    if (node < N_NODES) {
        float e = emb[node * DIM + d];
        float t1 = e * att_em_i[d];
        float t2 = e * att_em_j[d];
        float t3 = e * e;
#pragma unroll
        for (int m = 32; m >= 1; m >>= 1) {
            t1 += __shfl_xor(t1, m, 64);
            t2 += __shfl_xor(t2, m, 64);
            t3 += __shfl_xor(t3, m, 64);
        }
        if (d == 0) { edi[node] = t1; esi[node] = t2; nrm[node] = sqrtf(t3); }
    }
}

// ---------------- Kernel 3: top-20 per row of cos = G/(ni*nj) ----------------
__global__ __launch_bounds__(64) void k_topk(const float* __restrict__ g,
                                             const float* __restrict__ nrm,
                                             int* __restrict__ tk) {
    const int i = blockIdx.x;
    const int lane = threadIdx.x;
    const float ni = nrm[i];
    float v[16];
#pragma unroll
    for (int tt = 0; tt < 16; ++tt) {
        int j = lane + tt * 64;
        v[tt] = g[i * N_NODES + j] / (ni * nrm[j]);
    }
    for (int it = 0; it < TOPK; ++it) {
        float bv = v[0];
        int bt = 0;
#pragma unroll
        for (int tt = 1; tt < 16; ++tt)
            if (v[tt] > bv) { bv = v[tt]; bt = tt; }
        int bidx = lane + bt * 64;
#pragma unroll
        for (int m = 32; m >= 1; m >>= 1) {
            float ov = __shfl_xor(bv, m, 64);
            int oi = __shfl_xor(bidx, m, 64);
            if (ov > bv || (ov == bv && oi < bidx)) { bv = ov; bidx = oi; }
        }
        if (lane == 0) tk[i * TOPK + it] = bidx;
        if ((bidx & 63) == lane) v[bidx >> 6] = -3.0e38f;
    }
}

// ------- Kernel 4: attention softmax + aggregate + BN1/ReLU + emb mul + BN2/ReLU + head -------
__global__ __launch_bounds__(256) void k_main(
    const float* __restrict__ h, const float* __restrict__ emb,
    const float* __restrict__ dscal, const float* __restrict__ sscal,
    const float* __restrict__ edi, const float* __restrict__ esi,
    const int* __restrict__ tk, const float* __restrict__ gnn_bias,
    const float* __restrict__ g1, const float* __restrict__ b1,
    const float* __restrict__ m1, const float* __restrict__ v1,
    const float* __restrict__ g2, const float* __restrict__ b2,
    const float* __restrict__ m2, const float* __restrict__ v2,
    const float* __restrict__ outW, const float* __restrict__ outB,
    float* __restrict__ out) {
    const int node = blockIdx.x * 4 + (threadIdx.x >> 6);
    const int lane = threadIdx.x & 63;
    const int i = node & (N_NODES - 1);
    const int b = node >> 10;

    // lanes 0..19: top-k edges; lane 20: self loop
    int j = i;
    if (lane < TOPK) j = tk[i * TOPK + lane];
    const bool active = (lane <= TOPK);
    const bool masked = (lane < TOPK) && (j == i);
    float lg = -3.0e38f;
    if (active) {
        float l = dscal[node] + edi[i] + sscal[(b << 10) + j] + esi[j];
        l = (l > 0.f) ? l : 0.2f * l;          // leaky_relu(0.2)
        lg = masked ? -3.0e38f : l;
    }
    float m = lg;
#pragma unroll
    for (int mm = 32; mm >= 1; mm >>= 1) m = fmaxf(m, __shfl_xor(m, mm, 64));
    float ex = (active && !masked) ? expf(lg - m) : 0.f;
    float s = ex;
#pragma unroll
    for (int mm = 32; mm >= 1; mm >>= 1) s += __shfl_xor(s, mm, 64);
    const float alpha = ex / s;

    const int d = lane;
    float agg = 0.f;
#pragma unroll
    for (int k = 0; k <= TOPK; ++k) {
        float a = __shfl(alpha, k, 64);
        int jk = __shfl(j, k, 64);
        if (a != 0.f)  // wave-uniform branch
            agg += a * h[((b << 10) + jk) * DIM + d];
    }
    agg += gnn_bias[d];
    float x1 = (agg - m1[d]) * (1.f / sqrtf(v1[d] + 1e-5f)) * g1[d] + b1[d];
    x1 = fmaxf(x1, 0.f);
    float y = x1 * emb[i * DIM + d];
    float x2 = (y - m2[d]) * (1.f / sqrtf(v2[d] + 1e-5f)) * g2[d] + b2[d];
    x2 = fmaxf(x2, 0.f);
    float o = x2 * outW[d];
#pragma unroll
    for (int mm = 32; mm >= 1; mm >>= 1) o += __shfl_xor(o, mm, 64);
    if (d == 0) out[node] = o + outB[0];
}

extern "C" void kernel_launch(void* const* d_in, const int* in_sizes, int n_in,
                              void* d_out, int out_size, void* d_ws, size_t ws_size,
                              hipStream_t stream) {
    const float* data     = (const float*)d_in[0];
    const float* emb      = (const float*)d_in[1];
    const float* W_lin    = (const float*)d_in[2];
    const float* att_i    = (const float*)d_in[3];
    const float* att_j    = (const float*)d_in[4];
    const float* att_em_i = (const float*)d_in[5];
    const float* att_em_j = (const float*)d_in[6];
    const float* gnn_bias = (const float*)d_in[7];
    const float* g1 = (const float*)d_in[8];
    const float* b1 = (const float*)d_in[9];
    const float* m1 = (const float*)d_in[10];
    const float* v1 = (const float*)d_in[11];
    const float* g2 = (const float*)d_in[12];
    const float* b2 = (const float*)d_in[13];
    const float* m2 = (const float*)d_in[14];
    const float* v2 = (const float*)d_in[15];
    const float* outW = (const float*)d_in[16];
    const float* outB = (const float*)d_in[17];
    float* out = (float*)d_out;

    float* ws = (float*)d_ws;
    float* g     = ws;                         // 1M floats (4 MB)
    float* h     = ws + (1 << 20);             // 4M floats (16 MB)
    float* dscal = h + (size_t)BN_TOT * DIM;   // 65536
    float* sscal = dscal + BN_TOT;             // 65536
    float* edi   = sscal + BN_TOT;             // 1024
    float* esi   = edi + N_NODES;              // 1024
    float* nrm   = esi + N_NODES;              // 1024
    int*   tk    = (int*)(nrm + N_NODES);      // 1024*20 ints

    k_gemm_g<<<dim3(16, 16), 256, 0, stream>>>(emb, g);
    k_hscal<<<BN_TOT / 4, 256, 0, stream>>>(data, emb, W_lin, att_i, att_j,
                                            att_em_i, att_em_j,
                                            h, dscal, sscal, edi, esi, nrm);
    k_topk<<<N_NODES, 64, 0, stream>>>(g, nrm, tk);
    k_main<<<BN_TOT / 4, 256, 0, stream>>>(h, emb, dscal, sscal, edi, esi, tk,
                                           gnn_bias, g1, b1, m1, v1,
                                           g2, b2, m2, v2, outW, outB, out);
}

// Round 2
// 82.470 us; speedup vs baseline: 1.5054x; 1.5054x over previous
//
#include <hip/hip_runtime.h>

#define N_NODES 1024
#define B_SZ 64
#define F_IN 10
#define DIM 64
#define TOPK 20
#define BN_TOT (B_SZ * N_NODES)   // 65536

// ---------------- Kernel 1: G = emb @ emb^T (1024x1024, K=64) ----------------
__global__ __launch_bounds__(256) void k_gemm_g(const float* __restrict__ emb,
                                               float* __restrict__ g) {
    __shared__ float As[64][65];
    __shared__ float Bs[64][65];
    const int r0 = blockIdx.y * 64, c0 = blockIdx.x * 64;
    const int t = threadIdx.x;
#pragma unroll
    for (int k = 0; k < 16; ++k) {
        int idx = t + k * 256;
        int rr = idx >> 6, cc = idx & 63;
        As[rr][cc] = emb[(r0 + rr) * DIM + cc];
        Bs[rr][cc] = emb[(c0 + rr) * DIM + cc];
    }
    __syncthreads();
    const int tx = t & 15, ty = t >> 4;
    float acc[4][4] = {};
#pragma unroll 8
    for (int d = 0; d < 64; ++d) {
        float a[4], b[4];
#pragma unroll
        for (int ii = 0; ii < 4; ++ii) a[ii] = As[ty * 4 + ii][d];
#pragma unroll
        for (int jj = 0; jj < 4; ++jj) b[jj] = Bs[tx * 4 + jj][d];
#pragma unroll
        for (int ii = 0; ii < 4; ++ii)
#pragma unroll
            for (int jj = 0; jj < 4; ++jj) acc[ii][jj] += a[ii] * b[jj];
    }
#pragma unroll
    for (int ii = 0; ii < 4; ++ii)
#pragma unroll
        for (int jj = 0; jj < 4; ++jj)
            g[(r0 + ty * 4 + ii) * N_NODES + (c0 + tx * 4 + jj)] = acc[ii][jj];
}

// ---- Kernel 2 (k_prep): per-node emb scalars + norms; block 0 folds BN params ----
__global__ __launch_bounds__(256) void k_prep(
    const float* __restrict__ emb,
    const float* __restrict__ att_em_i, const float* __restrict__ att_em_j,
    const float* __restrict__ gnn_bias,
    const float* __restrict__ g1, const float* __restrict__ b1,
    const float* __restrict__ m1, const float* __restrict__ v1,
    const float* __restrict__ g2, const float* __restrict__ b2,
    const float* __restrict__ m2, const float* __restrict__ v2,
    float* __restrict__ edi, float* __restrict__ esi, float* __restrict__ nrm,
    float4* __restrict__ bnp) {
    const int node = blockIdx.x * 4 + (threadIdx.x >> 6);
    const int d = threadIdx.x & 63;
    float e = emb[node * DIM + d];
    float t1 = e * att_em_i[d];
    float t2 = e * att_em_j[d];
    float t3 = e * e;
#pragma unroll
    for (int m = 32; m >= 1; m >>= 1) {
        t1 += __shfl_xor(t1, m, 64);
        t2 += __shfl_xor(t2, m, 64);
        t3 += __shfl_xor(t3, m, 64);
    }
    if (d == 0) { edi[node] = t1; esi[node] = t2; nrm[node] = sqrtf(t3); }
    if (blockIdx.x == 0 && threadIdx.x < DIM) {
        const int q = threadIdx.x;
        float a1 = g1[q] * rsqrtf(v1[q] + 1e-5f);
        float c1 = (gnn_bias[q] - m1[q]) * a1 + b1[q];
        float a2 = g2[q] * rsqrtf(v2[q] + 1e-5f);
        float c2 = b2[q] - m2[q] * a2;
        bnp[q] = make_float4(a1, c1, a2, c2);
    }
}

// ---- Kernel 3 (k_hscal): h = x@W_lin, fold per-node dst/src attention scalars ----
__global__ __launch_bounds__(256) void k_hscal(
    const float* __restrict__ data, const float* __restrict__ W_lin,
    const float* __restrict__ att_i, const float* __restrict__ att_j,
    const float* __restrict__ edi, const float* __restrict__ esi,
    float* __restrict__ h, float* __restrict__ dd, float* __restrict__ ss) {
    const int node = blockIdx.x * 4 + (threadIdx.x >> 6);
    const int d = threadIdx.x & 63;
    const int i = node & (N_NODES - 1);
    float hv = 0.f;
#pragma unroll
    for (int f = 0; f < F_IN; ++f)
        hv = fmaf(data[node * F_IN + f], W_lin[f * DIM + d], hv);
    h[node * DIM + d] = hv;
    float s1 = hv * att_i[d];
    float s2 = hv * att_j[d];
#pragma unroll
    for (int m = 32; m >= 1; m >>= 1) {
        s1 += __shfl_xor(s1, m, 64);
        s2 += __shfl_xor(s2, m, 64);
    }
    if (d == 0) { dd[node] = s1 + edi[i]; ss[node] = s2 + esi[i]; }
}

// ---------------- Kernel 4: top-20 per row, 256 threads/row ----------------
__global__ __launch_bounds__(256) void k_topk(const float* __restrict__ g,
                                              const float* __restrict__ nrm,
                                              int* __restrict__ tk) {
    __shared__ float lv[4];
    __shared__ int li[4];
    const int i = blockIdx.x;
    const int t = threadIdx.x;
    const int lane = t & 63, w = t >> 6;
    const float ni = nrm[i];
    float4 gv = ((const float4*)(g + (size_t)i * N_NODES))[t];
    float4 nv = ((const float4*)nrm)[t];
    float v[4];
    v[0] = gv.x / (ni * nv.x);
    v[1] = gv.y / (ni * nv.y);
    v[2] = gv.z / (ni * nv.z);
    v[3] = gv.w / (ni * nv.w);
    for (int it = 0; it < TOPK; ++it) {
        float bv = v[0];
        int bq = 0;
#pragma unroll
        for (int q = 1; q < 4; ++q)
            if (v[q] > bv) { bv = v[q]; bq = q; }
        int bidx = t * 4 + bq;
#pragma unroll
        for (int m = 32; m >= 1; m >>= 1) {
            float ov = __shfl_xor(bv, m, 64);
            int oi = __shfl_xor(bidx, m, 64);
            if (ov > bv || (ov == bv && oi < bidx)) { bv = ov; bidx = oi; }
        }
        if (lane == 0) { lv[w] = bv; li[w] = bidx; }
        __syncthreads();
        float wv = lv[0];
        int wi = li[0];
#pragma unroll
        for (int q = 1; q < 4; ++q)
            if (lv[q] > wv || (lv[q] == wv && li[q] < wi)) { wv = lv[q]; wi = li[q]; }
        if (t == (wi >> 2)) v[wi & 3] = -3.0e38f;
        if (t == 0) tk[i * TOPK + it] = wi;
        __syncthreads();
    }
}

// ------- Kernel 5 (k_main): softmax + aggregate + folded BN/head, prefetched gathers -------
__global__ __launch_bounds__(256) void k_main(
    const float* __restrict__ h, const float* __restrict__ emb,
    const float* __restrict__ dd, const float* __restrict__ ss,
    const int* __restrict__ tk, const float4* __restrict__ bnp,
    const float* __restrict__ outW, const float* __restrict__ outB,
    float* __restrict__ out) {
    __shared__ int jbuf[4][24];
    __shared__ float abuf[4][24];
    const int bid = blockIdx.x;
    const int nb = (bid & 7) * 2048 + (bid >> 3);   // XCD swizzle: 8 batches per XCD
    const int w = threadIdx.x >> 6, lane = threadIdx.x & 63;
    const int node = nb * 4 + w;
    const int i = node & (N_NODES - 1);
    const int bbase = node & ~(N_NODES - 1);

    int j = i;
    if (lane < TOPK) j = tk[i * TOPK + lane];
    if (lane <= TOPK) jbuf[w][lane] = j;
    __builtin_amdgcn_wave_barrier();
    int4 jj4[5];
#pragma unroll
    for (int q = 0; q < 5; ++q) jj4[q] = ((int4*)jbuf[w])[q];
    int j20 = jbuf[w][20];

    // issue all 21 gathers up front (independent loads)
    const float* hb = h + (size_t)bbase * DIM + lane;
    float hv[21];
#pragma unroll
    for (int q = 0; q < 5; ++q) {
        hv[4 * q + 0] = hb[jj4[q].x * DIM];
        hv[4 * q + 1] = hb[jj4[q].y * DIM];
        hv[4 * q + 2] = hb[jj4[q].z * DIM];
        hv[4 * q + 3] = hb[jj4[q].w * DIM];
    }
    hv[20] = hb[j20 * DIM];

    // softmax over <=21 logits while loads are in flight
    const bool masked = (lane < TOPK) && (j == i);
    float lg = -3.0e38f;
    if (lane <= TOPK) {
        float l = dd[node] + ss[bbase + j];
        l = (l > 0.f) ? l : 0.2f * l;
        lg = masked ? -3.0e38f : l;
    }
    float m = lg;
#pragma unroll
    for (int mm = 16; mm >= 1; mm >>= 1) m = fmaxf(m, __shfl_xor(m, mm, 64));
    float ex = (lane <= TOPK && !masked) ? __expf(lg - m) : 0.f;
    float s = ex;
#pragma unroll
    for (int mm = 16; mm >= 1; mm >>= 1) s += __shfl_xor(s, mm, 64);
    const float alpha = ex / s;
    if (lane <= TOPK) abuf[w][lane] = alpha;
    __builtin_amdgcn_wave_barrier();
    float4 aa4[5];
#pragma unroll
    for (int q = 0; q < 5; ++q) aa4[q] = ((float4*)abuf[w])[q];
    float a20 = abuf[w][20];

    float agg = 0.f;
#pragma unroll
    for (int q = 0; q < 5; ++q) {
        agg = fmaf(aa4[q].x, hv[4 * q + 0], agg);
        agg = fmaf(aa4[q].y, hv[4 * q + 1], agg);
        agg = fmaf(aa4[q].z, hv[4 * q + 2], agg);
        agg = fmaf(aa4[q].w, hv[4 * q + 3], agg);
    }
    agg = fmaf(a20, hv[20], agg);

    const float4 p = bnp[lane];
    float x1 = fmaxf(fmaf(agg, p.x, p.y), 0.f);
    float y = x1 * emb[i * DIM + lane];
    float x2 = fmaxf(fmaf(y, p.z, p.w), 0.f);
    float o = x2 * outW[lane];
#pragma unroll
    for (int mm = 32; mm >= 1; mm >>= 1) o += __shfl_xor(o, mm, 64);
    if (lane == 0) out[node] = o + outB[0];
}

extern "C" void kernel_launch(void* const* d_in, const int* in_sizes, int n_in,
                              void* d_out, int out_size, void* d_ws, size_t ws_size,
                              hipStream_t stream) {
    const float* data     = (const float*)d_in[0];
    const float* emb      = (const float*)d_in[1];
    const float* W_lin    = (const float*)d_in[2];
    const float* att_i    = (const float*)d_in[3];
    const float* att_j    = (const float*)d_in[4];
    const float* att_em_i = (const float*)d_in[5];
    const float* att_em_j = (const float*)d_in[6];
    const float* gnn_bias = (const float*)d_in[7];
    const float* g1 = (const float*)d_in[8];
    const float* b1 = (const float*)d_in[9];
    const float* m1 = (const float*)d_in[10];
    const float* v1 = (const float*)d_in[11];
    const float* g2 = (const float*)d_in[12];
    const float* b2 = (const float*)d_in[13];
    const float* m2 = (const float*)d_in[14];
    const float* v2 = (const float*)d_in[15];
    const float* outW = (const float*)d_in[16];
    const float* outB = (const float*)d_in[17];
    float* out = (float*)d_out;

    float* ws = (float*)d_ws;
    float* g     = ws;                          // 1M floats (4 MB)
    float* h     = ws + (1 << 20);              // 4M floats (16 MB)
    float* dd    = h + (size_t)BN_TOT * DIM;    // 65536
    float* ss    = dd + BN_TOT;                 // 65536
    float* edi   = ss + BN_TOT;                 // 1024
    float* esi   = edi + N_NODES;               // 1024
    float* nrm   = esi + N_NODES;               // 1024
    int*   tk    = (int*)(nrm + N_NODES);       // 1024*20 ints
    float4* bnp  = (float4*)(tk + N_NODES * TOPK); // 64 float4

    k_gemm_g<<<dim3(16, 16), 256, 0, stream>>>(emb, g);
    k_prep<<<N_NODES / 4, 256, 0, stream>>>(emb, att_em_i, att_em_j, gnn_bias,
                                            g1, b1, m1, v1, g2, b2, m2, v2,
                                            edi, esi, nrm, bnp);
    k_hscal<<<BN_TOT / 4, 256, 0, stream>>>(data, W_lin, att_i, att_j, edi, esi,
                                            h, dd, ss);
    k_topk<<<N_NODES, 256, 0, stream>>>(g, nrm, tk);
    k_main<<<BN_TOT / 4, 256, 0, stream>>>(h, emb, dd, ss, tk, bnp, outW, outB, out);
}